// Round 2
// baseline (421.824 us; speedup 1.0000x reference)
//
#include <hip/hip_runtime.h>

// SNNLinear, exact-trajectory version.
//   delta = spikes @ W^T + b  accumulated in FP64 (order-insensitive to ~1e-13)
//   stored as hi/lo f32 pair: hi -> ss region of d_out, lo -> d_ws
//   scan (membrane update) entirely in FP64, outputs cast to f32.
//
// Outputs (flat, f32): ss[100,64,1024] | mem_out[64,1024] | hat_s[64,1024]
// hat_s forward == ss.mean(axis=0); hat_spikes GEMM is dead in forward.

#define THRV 15.0
#define T_STEPS 100
#define BATCH 64
#define IN_F 1024
#define OUT_F 1024
#define M_ROWS (T_STEPS * BATCH)   // 6400
#define BO (BATCH * OUT_F)         // 65536

// ---- GEMM: C[m,n] = (f64) sum_k A[m,k]*W[n,k] + b[n], hi/lo f32 output ----
// 64x64 tile per 256-thread block, 4x4 f64 microtile, TK=16, f32 LDS.
__global__ __launch_bounds__(256)
void gemm_f64(const float* __restrict__ A,    // [M,K] spikes (0/1)
              const float* __restrict__ W,    // [N,K]
              const float* __restrict__ bias, // [N]
              float* __restrict__ Chi,        // [M,N] hi part (= ss region)
              float* __restrict__ Clo) {      // [M,N] lo part (workspace)
    const int K = IN_F;
    __shared__ float As[16][68];
    __shared__ float Bs[16][68];

    const int bm = blockIdx.x;
    const int bn = blockIdx.y;
    const int t  = threadIdx.x;
    const int tx = t & 15;
    const int ty = t >> 4;
    const int lrow = t >> 2;
    const int lcol = t & 3;

    const float* Ag = A + (size_t)(bm * 64 + lrow) * K + lcol * 4;
    const float* Wg = W + (size_t)(bn * 64 + lrow) * K + lcol * 4;

    double acc[4][4];
#pragma unroll
    for (int i = 0; i < 4; ++i)
#pragma unroll
        for (int j = 0; j < 4; ++j) acc[i][j] = 0.0;

    for (int kt = 0; kt < K; kt += 16) {
        float4 a4 = *(const float4*)(Ag + kt);
        float4 w4 = *(const float4*)(Wg + kt);
        __syncthreads();
        const int kb = lcol * 4;
        As[kb + 0][lrow] = a4.x; As[kb + 1][lrow] = a4.y;
        As[kb + 2][lrow] = a4.z; As[kb + 3][lrow] = a4.w;
        Bs[kb + 0][lrow] = w4.x; Bs[kb + 1][lrow] = w4.y;
        Bs[kb + 2][lrow] = w4.z; Bs[kb + 3][lrow] = w4.w;
        __syncthreads();
#pragma unroll
        for (int k = 0; k < 16; ++k) {
            float4 av = *(const float4*)&As[k][ty * 4];
            float4 bv = *(const float4*)&Bs[k][tx * 4];
            double a0 = (double)av.x, a1 = (double)av.y;
            double a2 = (double)av.z, a3 = (double)av.w;
            double b0 = (double)bv.x, b1 = (double)bv.y;
            double b2 = (double)bv.z, b3 = (double)bv.w;
            acc[0][0] += a0 * b0; acc[0][1] += a0 * b1;
            acc[0][2] += a0 * b2; acc[0][3] += a0 * b3;
            acc[1][0] += a1 * b0; acc[1][1] += a1 * b1;
            acc[1][2] += a1 * b2; acc[1][3] += a1 * b3;
            acc[2][0] += a2 * b0; acc[2][1] += a2 * b1;
            acc[2][2] += a2 * b2; acc[2][3] += a2 * b3;
            acc[3][0] += a3 * b0; acc[3][1] += a3 * b1;
            acc[3][2] += a3 * b2; acc[3][3] += a3 * b3;
        }
    }

    const int row0 = bm * 64 + ty * 4;
    const int col0 = bn * 64 + tx * 4;
    const float4 bb = *(const float4*)(bias + col0);
    const double bd[4] = {(double)bb.x, (double)bb.y, (double)bb.z, (double)bb.w};
#pragma unroll
    for (int i = 0; i < 4; ++i) {
        float4 hi4, lo4;
        {
            double d0 = acc[i][0] + bd[0]; float h0 = (float)d0;
            double d1 = acc[i][1] + bd[1]; float h1 = (float)d1;
            double d2 = acc[i][2] + bd[2]; float h2 = (float)d2;
            double d3 = acc[i][3] + bd[3]; float h3 = (float)d3;
            hi4 = make_float4(h0, h1, h2, h3);
            lo4 = make_float4((float)(d0 - (double)h0), (float)(d1 - (double)h1),
                              (float)(d2 - (double)h2), (float)(d3 - (double)h3));
        }
        const size_t off = (size_t)(row0 + i) * OUT_F + col0;
        *(float4*)(Chi + off) = hi4;
        *(float4*)(Clo + off) = lo4;
    }
}

// ---- membrane scan, all math in f64, in place over the ss region ----
__global__ __launch_bounds__(256)
void snn_scan(float* __restrict__ out, const float* __restrict__ lo,
              const float* __restrict__ mem0) {
    const int bo = blockIdx.x * 256 + threadIdx.x;   // 0..65535
    double m = (double)mem0[bo];
    double cnt = 0.0;
    for (int t = 0; t < T_STEPS; ++t) {
        const size_t idx = (size_t)t * BO + bo;
        const double du = (double)out[idx] + (double)lo[idx];
        m += du;
        const double s = (m > THRV) ? 1.0 : 0.0;
        m = fmin(fmax(m, 0.0), THRV);   // clip(m, 0, thr)
        out[idx] = (float)s;            // spike (exact 0/1)
        cnt += s;
        m = m - m * s;                  // reset fired neurons (exact 0 when s=1)
    }
    out[(size_t)T_STEPS * BO + bo] = (float)m;                     // mem_out
    out[(size_t)T_STEPS * BO + BO + bo] = (float)(cnt / 100.0);    // hat_s
}

extern "C" void kernel_launch(void* const* d_in, const int* in_sizes, int n_in,
                              void* d_out, int out_size, void* d_ws, size_t ws_size,
                              hipStream_t stream) {
    const float* spikes = (const float*)d_in[0];  // [100,64,1024]
    const float* mem    = (const float*)d_in[1];  // [64,1024]
    // d_in[2] = hat_spikes: dead in forward (stop_gradient cancellation)
    const float* W      = (const float*)d_in[3];  // [1024,1024]
    const float* b      = (const float*)d_in[4];  // [1024]
    float* out = (float*)d_out;
    float* lo  = (float*)d_ws;  // 26.2 MB: lo part of f64 delta

    dim3 g1(M_ROWS / 64, OUT_F / 64);  // (100, 16)
    gemm_f64<<<g1, 256, 0, stream>>>(spikes, W, b, out, lo);
    snn_scan<<<dim3(BO / 256), 256, 0, stream>>>(out, lo, mem);
}

// Round 3
// 182.755 us; speedup vs baseline: 2.3081x; 2.3081x over previous
//
#include <hip/hip_runtime.h>

// SNNLinear, exact-trajectory via integer-digit f16 MFMA.
//   Wq = round(W * 2^40)  (43-bit int), split into 4 balanced base-2048 digits.
//   Each digit plane GEMM'd against spikes (0/1) with mfma_f32_16x16x32_f16:
//   all products and f32 accumulations are EXACT integers (< 2^20 << 2^24).
//   Recombine in int64 -> f64 du; du stored as f32 hi + f16 (lo*2^12).
//   Scan runs in f64 exactly as round 2.
//
// Outputs (flat, f32): ss[100,64,1024] | mem_out[64,1024] | hat_s[64,1024]
// ws: [0, 8MB) tiled digit planes f16 ; [8MB, 21.2MB) lo residual f16.

typedef __attribute__((ext_vector_type(8))) _Float16 half8;
typedef __attribute__((ext_vector_type(4))) float f32x4;

#define T_STEPS 100
#define BO 65536
#define K_DIM 1024
#define N_DIM 1024
#define M_ROWS 6400
#define BT_ELEMS (512 * 8192)          // 512 chunks x (4 planes * 64n * 32k)
#define LO_OFFSET ((size_t)BT_ELEMS * 2)  // 8388608 bytes

// ---- decompose W into 4 balanced base-2048 digit planes, GEMM-tiled ----
// chunk(bn,kt) = contiguous [p][n:64][k:32] f16 (16KB), chunk id = bn*32+kt
__global__ __launch_bounds__(256)
void decompose(const float* __restrict__ W, _Float16* __restrict__ Bt) {
    const int id = blockIdx.x * 256 + threadIdx.x;   // over 1M elements
    const int n = id >> 10, k = id & 1023;
    const float w = W[id];
    long long q = llrint((double)w * 0x1p40);        // |q| < 2^43
    int d[4];
#pragma unroll
    for (int p = 0; p < 3; ++p) {
        d[p] = (int)(((q + 1024) & 2047) - 1024);    // balanced digit in [-1024,1023]
        q = (q - d[p]) >> 11;                        // exact
    }
    d[3] = (int)q;                                   // |d3| <= ~705
    const size_t base = (size_t)((n >> 6) * 32 + (k >> 5)) * 8192
                      + (size_t)(n & 63) * 32 + (k & 31);
#pragma unroll
    for (int p = 0; p < 4; ++p)
        Bt[base + (size_t)p * 2048] = (_Float16)(float)d[p];
}

// ---- GEMM: 128(M)x64(N) block, 4 waves of 64x32, BK=32, 4 digit planes ----
__global__ __launch_bounds__(256, 2)
void gemm_mfma(const float* __restrict__ A,      // spikes [M,K] f32 (0/1)
               const _Float16* __restrict__ Bt,  // tiled digit planes
               const float* __restrict__ bias,   // [N]
               float* __restrict__ Chi,          // hi part -> ss region
               _Float16* __restrict__ Lo) {      // lo*4096 residual
    __shared__ _Float16 Al[128 * 32];
    __shared__ _Float16 Bl[4 * 64 * 32];
    const int bm = blockIdx.x, bn = blockIdx.y;
    const int tid = threadIdx.x;
    const int lane = tid & 63, wid = tid >> 6;
    const int wm0 = (wid >> 1) * 64, wn0 = (wid & 1) * 32;
    const int quad = lane >> 4, r16 = lane & 15;

    // fragment LDS pointers are loop-invariant (single-buffered)
    const half8* ap[4];
    const half8* bp[2][4];
#pragma unroll
    for (int i = 0; i < 4; ++i)
        ap[i] = (const half8*)&Al[(wm0 + i * 16 + r16) * 32 + quad * 8];
#pragma unroll
    for (int j = 0; j < 2; ++j)
#pragma unroll
        for (int p = 0; p < 4; ++p)
            bp[j][p] = (const half8*)&Bl[(p * 64 + wn0 + j * 16 + r16) * 32 + quad * 8];

    f32x4 acc[4][2][4] = {};

    // staging: A = 8 threads/row x 16B, 4 row-groups; B = linear 16KB chunk copy
    const int ar = tid >> 3;      // 0..31
    const int ac = tid & 7;       // 16B slot
    const float* Ag = A + (size_t)(bm * 128) * K_DIM + ac * 4;
    const _Float16* Bg = Bt + (size_t)(bn * 32) * 8192 + tid * 8;

    for (int kt = 0; kt < 32; ++kt) {
        float4 av[4];
#pragma unroll
        for (int it = 0; it < 4; ++it)
            av[it] = *(const float4*)(Ag + (size_t)(ar + it * 32) * K_DIM + kt * 32);
        half8 bv[4];
        const _Float16* bgk = Bg + (size_t)kt * 8192;
#pragma unroll
        for (int it = 0; it < 4; ++it)
            bv[it] = *(const half8*)(bgk + it * 2048);
        __syncthreads();   // previous iter's frag reads complete
#pragma unroll
        for (int it = 0; it < 4; ++it) {
            _Float16* dst = &Al[(ar + it * 32) * 32 + ac * 4];
            dst[0] = (_Float16)av[it].x; dst[1] = (_Float16)av[it].y;
            dst[2] = (_Float16)av[it].z; dst[3] = (_Float16)av[it].w;
        }
#pragma unroll
        for (int it = 0; it < 4; ++it)
            *(half8*)&Bl[it * 2048 + tid * 8] = bv[it];
        __syncthreads();

        half8 af[4];
#pragma unroll
        for (int i = 0; i < 4; ++i) af[i] = *ap[i];
#pragma unroll
        for (int j = 0; j < 2; ++j)
#pragma unroll
            for (int p = 0; p < 4; ++p) {
                const half8 bf = *bp[j][p];
#pragma unroll
                for (int i = 0; i < 4; ++i)
                    acc[i][j][p] = __builtin_amdgcn_mfma_f32_16x16x32_f16(
                        af[i], bf, acc[i][j][p], 0, 0, 0);
            }
    }

    // epilogue: exact int64 recombine -> f64 du -> hi/lo store
#pragma unroll
    for (int i = 0; i < 4; ++i)
#pragma unroll
        for (int j = 0; j < 2; ++j) {
            const int n_g = bn * 64 + wn0 + j * 16 + r16;
            const double bv = (double)bias[n_g];
#pragma unroll
            for (int e = 0; e < 4; ++e) {
                long long t = (long long)acc[i][j][3][e];
                t = t * 2048 + (long long)acc[i][j][2][e];
                t = t * 2048 + (long long)acc[i][j][1][e];
                t = t * 2048 + (long long)acc[i][j][0][e];
                const double du = (double)t * 0x1p-40 + bv;
                const float hi = (float)du;
                const float lo = (float)(du - (double)hi);
                const size_t m_g = (size_t)(bm * 128 + wm0 + i * 16 + quad * 4 + e);
                const size_t off = m_g * N_DIM + n_g;
                Chi[off] = hi;
                Lo[off] = (_Float16)(lo * 4096.0f);
            }
        }
}

// ---- membrane scan, f64, in place over ss; 4-deep load prefetch ----
__global__ __launch_bounds__(256)
void snn_scan(float* __restrict__ out, const _Float16* __restrict__ lo,
              const float* __restrict__ mem0) {
    const int bo = blockIdx.x * 256 + threadIdx.x;
    double m = (double)mem0[bo];
    double cnt = 0.0;
    for (int tb = 0; tb < T_STEPS; tb += 4) {
        float h[4], l[4];
#pragma unroll
        for (int u = 0; u < 4; ++u) {
            const size_t idx = (size_t)(tb + u) * BO + bo;
            h[u] = out[idx];
            l[u] = (float)lo[idx];
        }
#pragma unroll
        for (int u = 0; u < 4; ++u) {
            const double du = (double)h[u] + (double)l[u] * 0x1p-12;
            m += du;
            const double s = (m > 15.0) ? 1.0 : 0.0;
            m = fmin(fmax(m, 0.0), 15.0);
            out[(size_t)(tb + u) * BO + bo] = (float)s;
            cnt += s;
            m -= m * s;
        }
    }
    out[(size_t)T_STEPS * BO + bo] = (float)m;
    out[(size_t)(T_STEPS + 1) * BO + bo] = (float)(cnt * 0.01);
}

extern "C" void kernel_launch(void* const* d_in, const int* in_sizes, int n_in,
                              void* d_out, int out_size, void* d_ws, size_t ws_size,
                              hipStream_t stream) {
    const float* spikes = (const float*)d_in[0];  // [100,64,1024]
    const float* mem    = (const float*)d_in[1];  // [64,1024]
    // d_in[2] = hat_spikes: dead in forward
    const float* W      = (const float*)d_in[3];  // [1024,1024]
    const float* b      = (const float*)d_in[4];  // [1024]
    float* out = (float*)d_out;
    _Float16* Bt = (_Float16*)d_ws;
    _Float16* Lo = (_Float16*)((char*)d_ws + LO_OFFSET);

    decompose<<<dim3(4096), 256, 0, stream>>>(W, Bt);
    gemm_mfma<<<dim3(50, 16), 256, 0, stream>>>(spikes, Bt, b, out, Lo);
    snn_scan<<<dim3(BO / 256), 256, 0, stream>>>(out, Lo, mem);
}